// Round 7
// baseline (248.179 us; speedup 1.0000x reference)
//
#include <hip/hip_runtime.h>
#include <math.h>

// out[tok, d] = cos(dot(x[tok,:], W1) + b1) * cos(phi) * W2[d] + b2[d]
// D = 1024, tokens = B*S = 32768 (fixed by reference shape).
//
// Round 7: fused single kernel, LDS-based deep read pipeline.
// Diagnosis: every register-pipelined variant flatlined at ~2.5-3.3 TB/s
// because a wave can only hold 4-16 KB of reads in flight in VGPRs (and the
// scheduler sinks the loads anyway), while saturated-read latency needs
// ~50+ KB/CU outstanding. global_load_lds decouples in-flight bytes from
// VGPRs: each wave keeps a 4-deep rolling window of 4 KB rows streaming into
// its PRIVATE LDS region (no cross-wave sharing -> ZERO barriers -> no
// vmcnt(0) barrier drain), with counted inline-asm s_waitcnt vmcnt(N) that
// never drains to 0 mid-loop (T4). Stores are fire-and-forget and fused in.
//
// Geometry: 512 blocks x 4 waves; wave owns 16 contiguous tokens.
// LDS 64 KiB/block (4 waves x 4 slots x 4 KiB) -> 2 blocks/CU, all resident.
// In flight per wave: ~3 rows (12 KB) + stores, continuously.

#define EMBED_D 1024
#define NTOK    (8 * 4096)
#define ROWS    16          // tokens per wave
#define DEPTH   4           // pipeline depth (LDS row slots per wave)

typedef float f4 __attribute__((ext_vector_type(4)));

#define WAITVM(n) asm volatile("s_waitcnt vmcnt(" #n ")" ::: "memory")

// async global->LDS, 16B per lane; LDS dst = uniform base + lane*16
__device__ __forceinline__ void stage16(const float* g, float* l) {
    __builtin_amdgcn_global_load_lds(
        (const __attribute__((address_space(1))) float*)g,
        (__attribute__((address_space(3))) float*)l,
        16, 0, 0);
}

// stage one 4 KB row (4 instrs): seg s covers f4-indices [s*64, s*64+64)
__device__ __forceinline__ void stage_row(const float* xrow, float* lslot, int lane) {
    #pragma unroll
    for (int s = 0; s < 4; ++s)
        stage16(xrow + s * 256 + lane * 4, lslot + s * 256);
}

__device__ __forceinline__ float row_dot(const f4* lr, int lane, const f4* w1r) {
    float s = 0.f;
    #pragma unroll
    for (int c = 0; c < 4; ++c) {
        f4 xv = lr[c * 64 + lane];          // ds_read_b128, canonical pattern
        s = fmaf(xv.x, w1r[c].x, s);
        s = fmaf(xv.y, w1r[c].y, s);
        s = fmaf(xv.z, w1r[c].z, s);
        s = fmaf(xv.w, w1r[c].w, s);
    }
    return s;
}

// One pipeline step. W = literal vmcnt bound such that row i's 4 staging
// loads (and everything older) are complete. Wait ladder derived from the
// issue order [12 broadcast loads][S0..S3] then per-iter {stores, S_{i+4}}:
//   i=0..3: W = 12,16,20,24 ; i=4..12: W = 24 ; i=13,14,15: W = 20,16,12.
// Counting is invariant to within-iteration reorder of stores vs stage.
#define ROW_STEP(i, W)                                                      \
  do {                                                                      \
    WAITVM(W);                                                              \
    __builtin_amdgcn_sched_barrier(0);                                      \
    float sd = row_dot((const f4*)(lw + ((i) & (DEPTH - 1)) * EMBED_D),     \
                       lane, w1r);                                          \
    sd += __shfl_xor(sd, 32, 64);                                           \
    sd += __shfl_xor(sd, 16, 64);                                           \
    sd += __shfl_xor(sd, 8, 64);                                            \
    sd += __shfl_xor(sd, 4, 64);                                            \
    sd += __shfl_xor(sd, 2, 64);                                            \
    sd += __shfl_xor(sd, 1, 64);                                            \
    const float q = cosf(sd + b1v) * cphi;                                  \
    f4* orow = (f4*)(out + (size_t)(row0 + (i)) * EMBED_D);                 \
    _Pragma("unroll")                                                       \
    for (int c = 0; c < 4; ++c) {                                           \
      f4 o;                                                                 \
      o.x = fmaf(q, w2r[c].x, b2r[c].x);                                    \
      o.y = fmaf(q, w2r[c].y, b2r[c].y);                                    \
      o.z = fmaf(q, w2r[c].z, b2r[c].z);                                    \
      o.w = fmaf(q, w2r[c].w, b2r[c].w);                                    \
      orow[c * 64 + lane] = o;                                              \
    }                                                                       \
    if ((i) + DEPTH < ROWS)                                                 \
      stage_row(x + (size_t)(row0 + (i) + DEPTH) * EMBED_D,                 \
                lw + ((i) & (DEPTH - 1)) * EMBED_D, lane);                  \
  } while (0)

__global__ __launch_bounds__(256) void ffq_fused(
    const float* __restrict__ x,
    const float* __restrict__ W1,
    const float* __restrict__ b1,
    const float* __restrict__ phi,
    const float* __restrict__ W2,
    const float* __restrict__ b2,
    float* __restrict__ out)
{
    const int lane = threadIdx.x & 63;
    const int wib  = threadIdx.x >> 6;
    const int row0 = (blockIdx.x * 4 + wib) * ROWS;   // 16 contiguous tokens

    __shared__ __attribute__((aligned(16))) float lds[4 * DEPTH * EMBED_D];
    float* lw = lds + wib * DEPTH * EMBED_D;          // this wave's 16 KiB

    // Broadcast operands FIRST: oldest 12 entries in the vmcnt queue.
    const f4* w14 = (const f4*)W1;
    const f4* w24 = (const f4*)W2;
    const f4* b24 = (const f4*)b2;
    f4 w1r[4], w2r[4], b2r[4];
    #pragma unroll
    for (int c = 0; c < 4; ++c) {
        w1r[c] = w14[c * 64 + lane];
        w2r[c] = w24[c * 64 + lane];
        b2r[c] = b24[c * 64 + lane];
    }
    const float b1v  = b1[0];            // uniform -> s_load (lgkm, not vmcnt)
    const float cphi = cosf(phi[0]);

    __builtin_amdgcn_sched_barrier(0);   // pin: broadcasts before staging

    // Prologue: stage rows 0..3 (16 vmem instrs outstanding after this).
    #pragma unroll
    for (int d = 0; d < DEPTH; ++d)
        stage_row(x + (size_t)(row0 + d) * EMBED_D, lw + d * EMBED_D, lane);

    __builtin_amdgcn_sched_barrier(0);   // pin: staging before consume loop

    ROW_STEP(0, 12);
    ROW_STEP(1, 16);
    ROW_STEP(2, 20);
    ROW_STEP(3, 24);
    ROW_STEP(4, 24);
    ROW_STEP(5, 24);
    ROW_STEP(6, 24);
    ROW_STEP(7, 24);
    ROW_STEP(8, 24);
    ROW_STEP(9, 24);
    ROW_STEP(10, 24);
    ROW_STEP(11, 24);
    ROW_STEP(12, 24);
    ROW_STEP(13, 20);
    ROW_STEP(14, 16);
    ROW_STEP(15, 12);
}

extern "C" void kernel_launch(void* const* d_in, const int* in_sizes, int n_in,
                              void* d_out, int out_size, void* d_ws, size_t ws_size,
                              hipStream_t stream) {
    const float* x   = (const float*)d_in[0];
    const float* W1  = (const float*)d_in[1];
    const float* b1  = (const float*)d_in[2];
    const float* phi = (const float*)d_in[3];
    const float* W2  = (const float*)d_in[4];
    const float* b2  = (const float*)d_in[5];
    float* out = (float*)d_out;

    // 32768 tokens / (4 waves * 16 rows) = 512 blocks, all co-resident
    // (2 blocks/CU, LDS-limited). Single launch, no workspace.
    ffq_fused<<<NTOK / (4 * ROWS), 256, 0, stream>>>(x, W1, b1, phi, W2, b2, out);
}